// Round 2
// baseline (288.364 us; speedup 1.0000x reference)
//
#include <hip/hip_runtime.h>
#include <math.h>

#define Bn 512
#define Sn 1024
#define Tn 48
#define BG 16              // batches per wave
#define NBLK (Bn / BG)     // 32 forward blocks

typedef _Float16 h4 __attribute__((ext_vector_type(4)));
typedef float    f4 __attribute__((ext_vector_type(4)));

static constexpr float LOG2E = 1.4426950408889634f;
static constexpr float LN2f  = 0.6931471805599453f;

// NOTE: do NOT gate this on __has_builtin — it returns 0 in the host pass
// (aux-target builtins are parseable but not __has_builtin-visible) and the
// macro ends up undefined for host compilation. Unconditional is correct.
#define MFMA16(A, B, C) __builtin_amdgcn_mfma_f32_16x16x16f16((A), (B), (C), 0, 0, 0)

// Forward (denominator) kernel: one wave handles 16 batches.
// State W[k=0..47, b=0..15] lives in 3 B-fragments (f16). Per step:
//   D = A * B   (A = 2^(trans*log2e - mtg), 3x3 static f16 tiles, 9 MFMAs)
//   W'[j,b] = D[j,b] * 2^(em[b,s,j]*log2e - 6 - shift_b)   (stale-by-2 renorm)
// 16x16x16 C/D layout (col=lane&15,row=4g+i) == B layout (col=lane&15,k=4g+i)
// so D feeds next step's B with only f32->f16 converts, no cross-lane moves.
__global__ __launch_bounds__(64, 1)
__attribute__((amdgpu_waves_per_eu(1)))
void crf_fwd_mfma(const float* __restrict__ em,
                  const float* __restrict__ mask,
                  const float* __restrict__ trans,
                  const float* __restrict__ startt,
                  const float* __restrict__ endt,
                  float* __restrict__ den_out)
{
  const int l    = threadIdx.x;
  const int c16  = l & 15;   // A-row / B,D-col within a tile
  const int g    = l >> 4;   // lane group: rows/ks 4g..4g+3
  const int bcol = blockIdx.x * BG + c16;

  // ---- static A fragments + global trans max (log2 domain) ----
  float tl[3][3][4];
  float mt = -1e30f;
  #pragma unroll
  for (int rt = 0; rt < 3; ++rt)
    #pragma unroll
    for (int kt = 0; kt < 3; ++kt) {
      const f4 t4 = *(const f4*)(trans + (16 * rt + c16) * Tn + 16 * kt + 4 * g);
      #pragma unroll
      for (int i = 0; i < 4; ++i) {
        const float v = t4[i] * LOG2E;
        tl[rt][kt][i] = v;
        mt = fmaxf(mt, v);
      }
    }
  #pragma unroll
  for (int off = 1; off < 64; off <<= 1) mt = fmaxf(mt, __shfl_xor(mt, off));
  const float mtg = mt;

  h4 Afr[3][3];
  #pragma unroll
  for (int rt = 0; rt < 3; ++rt)
    #pragma unroll
    for (int kt = 0; kt < 3; ++kt) {
      h4 r;
      #pragma unroll
      for (int i = 0; i < 4; ++i)
        r[i] = (_Float16)__builtin_amdgcn_exp2f(tl[rt][kt][i] - mtg);
      Afr[rt][kt] = r;
    }

  const float* __restrict__ emL = em + ((size_t)bcol * Sn) * Tn + 4 * g;
  const float* __restrict__ mkL = mask + (size_t)bcol * Sn;

  // ---- init (step 0): per-column exact max normalization ----
  h4 Bfr[3];
  float M, cnt = 0.0f;
  {
    float sc[3][4];
    float lm = -1e30f;
    #pragma unroll
    for (int kt = 0; kt < 3; ++kt) {
      const f4 st = *(const f4*)(startt + 16 * kt + 4 * g);
      const f4 e0 = *(const f4*)(emL + 16 * kt);
      #pragma unroll
      for (int i = 0; i < 4; ++i) {
        const float v = (st[i] + e0[i]) * LOG2E;
        sc[kt][i] = v;
        lm = fmaxf(lm, v);
      }
    }
    lm = fmaxf(lm, __shfl_xor(lm, 16));
    lm = fmaxf(lm, __shfl_xor(lm, 32));
    M = lm;
    #pragma unroll
    for (int kt = 0; kt < 3; ++kt) {
      h4 r;
      #pragma unroll
      for (int i = 0; i < 4; ++i)
        r[i] = (_Float16)__builtin_amdgcn_exp2f(sc[kt][i] - lm);
      Bfr[kt] = r;
    }
  }

  float wf[3][4];

  auto do_step = [&](const f4 e0, const f4 e1, const f4 e2, float mk, float sh) {
    f4 a0 = {0.f, 0.f, 0.f, 0.f}, a1 = a0, a2 = a0;
    a0 = MFMA16(Afr[0][0], Bfr[0], a0);
    a1 = MFMA16(Afr[1][0], Bfr[0], a1);
    a2 = MFMA16(Afr[2][0], Bfr[0], a2);
    a0 = MFMA16(Afr[0][1], Bfr[1], a0);
    a1 = MFMA16(Afr[1][1], Bfr[1], a1);
    a2 = MFMA16(Afr[2][1], Bfr[1], a2);
    a0 = MFMA16(Afr[0][2], Bfr[2], a0);
    a1 = MFMA16(Afr[1][2], Bfr[2], a1);
    a2 = MFMA16(Afr[2][2], Bfr[2], a2);
    const float bias = -6.0f - sh;
    #pragma unroll
    for (int i = 0; i < 4; ++i) {
      wf[0][i] = a0[i] * __builtin_amdgcn_exp2f(fmaf(e0[i], LOG2E, bias));
      wf[1][i] = a1[i] * __builtin_amdgcn_exp2f(fmaf(e1[i], LOG2E, bias));
      wf[2][i] = a2[i] * __builtin_amdgcn_exp2f(fmaf(e2[i], LOG2E, bias));
    }
    const bool on = (mk > 0.0f);
    #pragma unroll
    for (int rt = 0; rt < 3; ++rt) {
      h4 nb;
      #pragma unroll
      for (int i = 0; i < 4; ++i) nb[i] = (_Float16)wf[rt][i];  // RTN, unbiased
      Bfr[rt] = on ? nb : Bfr[rt];
    }
    M = fmaf(mk, sh, M);   // shift applied only on unmasked update
    cnt += mk;
  };

  // Per-column power-of-2 excess, measured POST-apply (stable cadence).
  auto measure = [&]() -> float {
    float m = wf[0][0];
    #pragma unroll
    for (int rt = 0; rt < 3; ++rt)
      #pragma unroll
      for (int i = 0; i < 4; ++i) m = fmaxf(m, wf[rt][i]);
    m = fmaxf(m, __shfl_xor(m, 16));
    m = fmaxf(m, __shfl_xor(m, 32));
    int eb = ((__float_as_int(m) >> 23) & 0xff) - 127;
    eb = eb < -24 ? -24 : (eb > 40 ? 40 : eb);
    return (float)eb;
  };

  auto load3 = [&](int s, f4& x, f4& y, f4& z) {
    const float* p = emL + (size_t)s * Tn;
    x = *(const f4*)(p);
    y = *(const f4*)(p + 16);
    z = *(const f4*)(p + 32);
  };

  float shA = 0.0f, shP = 0.0f;

  // prologue: steps 1..3 (apply at odd steps, measure right after apply)
  {
    f4 x, y, z;
    load3(1, x, y, z); do_step(x, y, z, mkL[1], 0.0f); shA = measure();
    load3(2, x, y, z); do_step(x, y, z, mkL[2], 0.0f);
    load3(3, x, y, z); do_step(x, y, z, mkL[3], shA);  shP = measure();
  }

  f4 EA[4][3], EB[4][3], mkA, mkB;
  auto load_chunk = [&](int s0, f4 (&E)[4][3], f4& mk4) {
    #pragma unroll
    for (int st = 0; st < 4; ++st) load3(s0 + st, E[st][0], E[st][1], E[st][2]);
    mk4 = *(const f4*)(mkL + s0);
  };
  auto run_chunk = [&](const f4 (&E)[4][3], const f4 mk4) {
    do_step(E[0][0], E[0][1], E[0][2], mk4[0], 0.0f);
    do_step(E[1][0], E[1][1], E[1][2], mk4[1], shP); shA = measure();
    do_step(E[2][0], E[2][1], E[2][2], mk4[2], 0.0f);
    do_step(E[3][0], E[3][1], E[3][2], mk4[3], shA); shP = measure();
  };

  // double-buffered 4-step chunks, prefetch distance = 4 steps
  load_chunk(4, EA, mkA);
  load_chunk(8, EB, mkB);
  for (int s0 = 4; s0 + 15 <= Sn - 1; s0 += 8) {   // s0 = 4..1004
    run_chunk(EA, mkA);
    load_chunk(s0 + 8, EA, mkA);
    run_chunk(EB, mkB);
    load_chunk(s0 + 12, EB, mkB);
  }
  run_chunk(EA, mkA);           // 1012..1015
  load_chunk(Sn - 4, EA, mkA);  // tail data 1020..1023
  run_chunk(EB, mkB);           // 1016..1019
  run_chunk(EA, mkA);           // 1020..1023

  // epilogue: den[b] = (M + (mtg+6)*cnt + log2(sum_j w[j,b]*2^end2[j])) * ln2
  float z = 0.0f;
  #pragma unroll
  for (int kt = 0; kt < 3; ++kt) {
    const f4 ev = *(const f4*)(endt + 16 * kt + 4 * g);
    #pragma unroll
    for (int i = 0; i < 4; ++i)
      z += (float)Bfr[kt][i] * __builtin_amdgcn_exp2f(ev[i] * LOG2E);
  }
  z += __shfl_xor(z, 16);
  z += __shfl_xor(z, 32);
  const float den = (M + (mtg + 6.0f) * cnt + __builtin_amdgcn_logf(z)) * LN2f;
  if (l < 16) den_out[bcol] = den;
}

// Numerator: no recurrence -> fully parallel gather+reduce. One block per batch.
__global__ __launch_bounds__(256) void crf_numer(
    const float* __restrict__ em, const int* __restrict__ tags,
    const float* __restrict__ mask, const float* __restrict__ trans,
    const float* __restrict__ startt, const float* __restrict__ endt,
    float* __restrict__ num_out)
{
  const int b = blockIdx.x, t = threadIdx.x;
  const int*   tgb = tags + (size_t)b * Sn;
  const float* mkb = mask + (size_t)b * Sn;
  const float* emb = em + (size_t)b * Sn * Tn;

  const int s0 = t * 4;
  const int4 tg = *(const int4*)(tgb + s0);
  const f4   mk = *(const f4*)(mkb + s0);
  const int  tprev = (t == 0) ? 0 : tgb[s0 - 1];
  const int  tgarr[5] = {tprev, tg.x, tg.y, tg.z, tg.w};

  float acc  = 0.0f;
  float msum = mk[0] + mk[1] + mk[2] + mk[3];
  #pragma unroll
  for (int i = 0; i < 4; ++i) {
    const int s = s0 + i;
    if (s >= 1)
      acc += mk[i] * (emb[(size_t)s * Tn + tgarr[i + 1]] +
                      trans[tgarr[i + 1] * Tn + tgarr[i]]);
  }
  #pragma unroll
  for (int off = 32; off; off >>= 1) {
    acc  += __shfl_xor(acc, off);
    msum += __shfl_xor(msum, off);
  }
  __shared__ float ra[4], rm[4];
  if ((t & 63) == 0) { ra[t >> 6] = acc; rm[t >> 6] = msum; }
  __syncthreads();
  if (t == 0) {
    const float a = ra[0] + ra[1] + ra[2] + ra[3];
    const float m = rm[0] + rm[1] + rm[2] + rm[3];
    int last = (int)(m + 0.5f) - 1;
    if (last < 0) last = 0;
    const int lt = tgb[last];
    const int t0 = tgb[0];
    num_out[b] = startt[t0] + emb[t0] + a + endt[lt];
  }
}

__global__ __launch_bounds__(512) void reduce_loss(const float* __restrict__ den,
                                                   const float* __restrict__ num,
                                                   float* __restrict__ out) {
  __shared__ float red[8];
  const int t = threadIdx.x;
  float v = den[t] - num[t];
  #pragma unroll
  for (int off = 32; off; off >>= 1) v += __shfl_xor(v, off);
  if ((t & 63) == 0) red[t >> 6] = v;
  __syncthreads();
  if (t == 0) {
    float s = 0.f;
    #pragma unroll
    for (int wv = 0; wv < 8; ++wv) s += red[wv];
    out[0] = s * (1.0f / 512.0f);
  }
}

extern "C" void kernel_launch(void* const* d_in, const int* in_sizes, int n_in,
                              void* d_out, int out_size, void* d_ws, size_t ws_size,
                              hipStream_t stream) {
  const float* emissions = (const float*)d_in[0];
  const int*   tags      = (const int*)d_in[1];
  const float* mask      = (const float*)d_in[2];
  const float* trans     = (const float*)d_in[3];
  const float* startt    = (const float*)d_in[4];
  const float* endt      = (const float*)d_in[5];
  float* den_ws = (float*)d_ws;         // 512 floats
  float* num_ws = den_ws + Bn;          // 512 floats

  crf_numer<<<Bn, 256, 0, stream>>>(emissions, tags, mask, trans, startt, endt, num_ws);
  crf_fwd_mfma<<<NBLK, 64, 0, stream>>>(emissions, mask, trans, startt, endt, den_ws);
  reduce_loss<<<1, 512, 0, stream>>>(den_ws, num_ws, (float*)d_out);
}

// Round 3
// 205.486 us; speedup vs baseline: 1.4033x; 1.4033x over previous
//
#include <hip/hip_runtime.h>
#include <math.h>

#define Bn 512
#define Sn 1024
#define Tn 48
#define BG 16              // batches per wave/block
#define NBLK (Bn / BG)     // 32 forward blocks
#define KBLK 16            // steps per LDS block
#define NKB (Sn / KBLK)    // 64 blocks of steps

typedef _Float16 h4 __attribute__((ext_vector_type(4)));
typedef float    f4 __attribute__((ext_vector_type(4)));

static constexpr float LOG2E = 1.4426950408889634f;
static constexpr float LN2f  = 0.6931471805599453f;

// Unconditional: __has_builtin for amdgcn builtins returns 0 in the host pass.
#define MFMA16(A, B, C) __builtin_amdgcn_mfma_f32_16x16x16f16((A), (B), (C), 0, 0, 0)

// Producer/consumer forward kernel. Wave 0 = serial chain (16 batches via
// 3x3 MFMA tiles); waves 1-3 = exp2(em*log2e - 6) precompute into LDS.
// Numerics of the chain are identical to the round-2 passing kernel; the
// exp2-with-bias is replaced by (LDS ehat) * (exact 2^-sh f32 multiply).
__global__ __launch_bounds__(256)
void crf_fwd_mfma(const float* __restrict__ em,
                  const float* __restrict__ mask,
                  const float* __restrict__ trans,
                  const float* __restrict__ startt,
                  const float* __restrict__ endt,
                  float* __restrict__ den_out)
{
  const int tid = threadIdx.x;
  const int wid = tid >> 6;
  const int l   = tid & 63;
  const int c16 = l & 15;   // A-row / B,D-col within a tile (= batch slot)
  const int g   = l >> 4;   // lane group: rows/ks 4g..4g+3
  const int bcol = blockIdx.x * BG + c16;

  // [buf][step][row-tile][lane][4] f32 ehat values. 2*16*3*64*16B = 96 KiB.
  __shared__ __align__(16) float ebuf[2][KBLK][3][64][4];

  const float* __restrict__ emL = em + ((size_t)bcol * Sn) * Tn + 4 * g;
  const float* __restrict__ mkL = mask + (size_t)bcol * Sn;

  // ---------------- producer: fill one 16-step block ----------------
  auto fillblk = [&](int blk) {
    const int buf = blk & 1;
    for (int sl = wid - 1; sl < KBLK; sl += 3) {
      const int s = blk * KBLK + sl;
      const float* p = emL + (size_t)s * Tn;
      const f4 x = *(const f4*)(p);
      const f4 y = *(const f4*)(p + 16);
      const f4 z = *(const f4*)(p + 32);
      f4 ex, ey, ez;
      #pragma unroll
      for (int i = 0; i < 4; ++i) {
        ex[i] = __builtin_amdgcn_exp2f(fmaf(x[i], LOG2E, -6.0f));
        ey[i] = __builtin_amdgcn_exp2f(fmaf(y[i], LOG2E, -6.0f));
        ez[i] = __builtin_amdgcn_exp2f(fmaf(z[i], LOG2E, -6.0f));
      }
      *(f4*)&ebuf[buf][sl][0][l][0] = ex;
      *(f4*)&ebuf[buf][sl][1][l][0] = ey;
      *(f4*)&ebuf[buf][sl][2][l][0] = ez;
    }
  };

  // ---------------- consumer persistent state ----------------
  h4 Afr[3][3];
  h4 Bfr[3];
  float M = 0.0f, cnt = 0.0f, mtg = 0.0f;
  float wf[3][4];
  float shP = 0.0f, shA = 0.0f, scP = 1.0f, scA = 1.0f;
  f4 mkcur[4], mknext[4];

  if (wid == 0) {
    // static A fragments + global trans max (log2 domain)
    float tl[3][3][4];
    float mt = -1e30f;
    #pragma unroll
    for (int rt = 0; rt < 3; ++rt)
      #pragma unroll
      for (int kt = 0; kt < 3; ++kt) {
        const f4 t4 = *(const f4*)(trans + (16 * rt + c16) * Tn + 16 * kt + 4 * g);
        #pragma unroll
        for (int i = 0; i < 4; ++i) {
          const float v = t4[i] * LOG2E;
          tl[rt][kt][i] = v;
          mt = fmaxf(mt, v);
        }
      }
    #pragma unroll
    for (int off = 1; off < 64; off <<= 1) mt = fmaxf(mt, __shfl_xor(mt, off));
    mtg = mt;
    #pragma unroll
    for (int rt = 0; rt < 3; ++rt)
      #pragma unroll
      for (int kt = 0; kt < 3; ++kt) {
        h4 r;
        #pragma unroll
        for (int i = 0; i < 4; ++i)
          r[i] = (_Float16)__builtin_amdgcn_exp2f(tl[rt][kt][i] - mtg);
        Afr[rt][kt] = r;
      }

    // init (step 0): per-column exact max normalization
    {
      float sc[3][4];
      float lm = -1e30f;
      #pragma unroll
      for (int kt = 0; kt < 3; ++kt) {
        const f4 st = *(const f4*)(startt + 16 * kt + 4 * g);
        const f4 e0 = *(const f4*)(emL + 16 * kt);
        #pragma unroll
        for (int i = 0; i < 4; ++i) {
          const float v = (st[i] + e0[i]) * LOG2E;
          sc[kt][i] = v;
          lm = fmaxf(lm, v);
        }
      }
      lm = fmaxf(lm, __shfl_xor(lm, 16));
      lm = fmaxf(lm, __shfl_xor(lm, 32));
      M = lm;
      #pragma unroll
      for (int kt = 0; kt < 3; ++kt) {
        h4 r;
        #pragma unroll
        for (int i = 0; i < 4; ++i)
          r[i] = (_Float16)__builtin_amdgcn_exp2f(sc[kt][i] - lm);
        Bfr[kt] = r;
      }
    }
    // mask for block 0 + issue prefetch for block 1
    #pragma unroll
    for (int q = 0; q < 4; ++q) mkcur[q] = *(const f4*)(mkL + 4 * q);
    #pragma unroll
    for (int q = 0; q < 4; ++q) mknext[q] = *(const f4*)(mkL + KBLK + 4 * q);
  } else {
    fillblk(0);
  }

  auto do_step = [&](const f4 e0, const f4 e1, const f4 e2, float mk,
                     float sc, float sh) {
    f4 a0 = {0.f, 0.f, 0.f, 0.f}, a1 = a0, a2 = a0;
    a0 = MFMA16(Afr[0][0], Bfr[0], a0);
    a1 = MFMA16(Afr[1][0], Bfr[0], a1);
    a2 = MFMA16(Afr[2][0], Bfr[0], a2);
    a0 = MFMA16(Afr[0][1], Bfr[1], a0);
    a1 = MFMA16(Afr[1][1], Bfr[1], a1);
    a2 = MFMA16(Afr[2][1], Bfr[1], a2);
    a0 = MFMA16(Afr[0][2], Bfr[2], a0);
    a1 = MFMA16(Afr[1][2], Bfr[2], a1);
    a2 = MFMA16(Afr[2][2], Bfr[2], a2);
    #pragma unroll
    for (int i = 0; i < 4; ++i) {
      wf[0][i] = a0[i] * e0[i] * sc;
      wf[1][i] = a1[i] * e1[i] * sc;
      wf[2][i] = a2[i] * e2[i] * sc;
    }
    const bool on = (mk > 0.0f);
    #pragma unroll
    for (int rt = 0; rt < 3; ++rt) {
      h4 nb;
      #pragma unroll
      for (int i = 0; i < 4; ++i) nb[i] = (_Float16)wf[rt][i];  // RTN
      Bfr[rt] = on ? nb : Bfr[rt];
    }
    M = fmaf(mk, sh, M);
    cnt += mk;
  };

  auto measure = [&](float& sh, float& sc) {
    float m = fmaxf(fmaxf(fmaxf(wf[0][0], wf[0][1]), fmaxf(wf[0][2], wf[0][3])),
               fmaxf(fmaxf(fmaxf(wf[1][0], wf[1][1]), fmaxf(wf[1][2], wf[1][3])),
                     fmaxf(fmaxf(wf[2][0], wf[2][1]), fmaxf(wf[2][2], wf[2][3]))));
    m = fmaxf(m, __shfl_xor(m, 16));
    m = fmaxf(m, __shfl_xor(m, 32));
    int eb = ((__float_as_int(m) >> 23) & 0xff) - 127;
    eb = eb < -24 ? -24 : (eb > 40 ? 40 : eb);
    sh = (float)eb;
    sc = __int_as_float((127 - eb) << 23);   // exact 2^-eb
  };

  auto consume = [&](int blk) {
    const int buf = blk & 1;
    const int sstart = (blk == 0) ? 1 : 0;
    if (blk > 0) {
      #pragma unroll
      for (int q = 0; q < 4; ++q) mkcur[q] = mknext[q];
      if (blk + 1 < NKB) {
        #pragma unroll
        for (int q = 0; q < 4; ++q)
          mknext[q] = *(const f4*)(mkL + (blk + 1) * KBLK + 4 * q);
      }
    }
    f4 EH[2][3];
    #pragma unroll
    for (int rt = 0; rt < 3; ++rt) {
      EH[0][rt] = *(const f4*)&ebuf[buf][0][rt][l][0];
      EH[1][rt] = *(const f4*)&ebuf[buf][1][rt][l][0];
    }
    #pragma unroll
    for (int sl = 0; sl < KBLK; ++sl) {
      if (sl >= sstart) {
        const f4 e0 = EH[sl & 1][0];
        const f4 e1 = EH[sl & 1][1];
        const f4 e2 = EH[sl & 1][2];
        const float mk = mkcur[sl >> 2][sl & 3];
        if ((sl & 3) == 1)      { do_step(e0, e1, e2, mk, scP, shP); measure(shA, scA); }
        else if ((sl & 3) == 3) { do_step(e0, e1, e2, mk, scA, shA); measure(shP, scP); }
        else                    { do_step(e0, e1, e2, mk, 1.0f, 0.0f); }
      }
      if (sl + 2 < KBLK) {
        #pragma unroll
        for (int rt = 0; rt < 3; ++rt)
          EH[sl & 1][rt] = *(const f4*)&ebuf[buf][sl + 2][rt][l][0];
      }
    }
  };

  __syncthreads();
  for (int blk = 0; blk < NKB; ++blk) {
    if (wid == 0)             consume(blk);
    else if (blk + 1 < NKB)   fillblk(blk + 1);
    __syncthreads();
  }

  if (wid == 0) {
    // den[b] = (M + (mtg+6)*cnt + log2(sum_j w[j,b]*2^end2[j])) * ln2
    float z = 0.0f;
    #pragma unroll
    for (int kt = 0; kt < 3; ++kt) {
      const f4 ev = *(const f4*)(endt + 16 * kt + 4 * g);
      #pragma unroll
      for (int i = 0; i < 4; ++i)
        z += (float)Bfr[kt][i] * __builtin_amdgcn_exp2f(ev[i] * LOG2E);
    }
    z += __shfl_xor(z, 16);
    z += __shfl_xor(z, 32);
    const float den = (M + (mtg + 6.0f) * cnt + __builtin_amdgcn_logf(z)) * LN2f;
    if (l < 16) den_out[bcol] = den;
  }
}

// Numerator: no recurrence -> fully parallel gather+reduce. One block per batch.
__global__ __launch_bounds__(256) void crf_numer(
    const float* __restrict__ em, const int* __restrict__ tags,
    const float* __restrict__ mask, const float* __restrict__ trans,
    const float* __restrict__ startt, const float* __restrict__ endt,
    float* __restrict__ num_out)
{
  const int b = blockIdx.x, t = threadIdx.x;
  const int*   tgb = tags + (size_t)b * Sn;
  const float* mkb = mask + (size_t)b * Sn;
  const float* emb = em + (size_t)b * Sn * Tn;

  const int s0 = t * 4;
  const int4 tg = *(const int4*)(tgb + s0);
  const f4   mk = *(const f4*)(mkb + s0);
  const int  tprev = (t == 0) ? 0 : tgb[s0 - 1];
  const int  tgarr[5] = {tprev, tg.x, tg.y, tg.z, tg.w};

  float acc  = 0.0f;
  float msum = mk[0] + mk[1] + mk[2] + mk[3];
  #pragma unroll
  for (int i = 0; i < 4; ++i) {
    const int s = s0 + i;
    if (s >= 1)
      acc += mk[i] * (emb[(size_t)s * Tn + tgarr[i + 1]] +
                      trans[tgarr[i + 1] * Tn + tgarr[i]]);
  }
  #pragma unroll
  for (int off = 32; off; off >>= 1) {
    acc  += __shfl_xor(acc, off);
    msum += __shfl_xor(msum, off);
  }
  __shared__ float ra[4], rm[4];
  if ((t & 63) == 0) { ra[t >> 6] = acc; rm[t >> 6] = msum; }
  __syncthreads();
  if (t == 0) {
    const float a = ra[0] + ra[1] + ra[2] + ra[3];
    const float m = rm[0] + rm[1] + rm[2] + rm[3];
    int last = (int)(m + 0.5f) - 1;
    if (last < 0) last = 0;
    const int lt = tgb[last];
    const int t0 = tgb[0];
    num_out[b] = startt[t0] + emb[t0] + a + endt[lt];
  }
}

__global__ __launch_bounds__(512) void reduce_loss(const float* __restrict__ den,
                                                   const float* __restrict__ num,
                                                   float* __restrict__ out) {
  __shared__ float red[8];
  const int t = threadIdx.x;
  float v = den[t] - num[t];
  #pragma unroll
  for (int off = 32; off; off >>= 1) v += __shfl_xor(v, off);
  if ((t & 63) == 0) red[t >> 6] = v;
  __syncthreads();
  if (t == 0) {
    float s = 0.f;
    #pragma unroll
    for (int wv = 0; wv < 8; ++wv) s += red[wv];
    out[0] = s * (1.0f / 512.0f);
  }
}

extern "C" void kernel_launch(void* const* d_in, const int* in_sizes, int n_in,
                              void* d_out, int out_size, void* d_ws, size_t ws_size,
                              hipStream_t stream) {
  const float* emissions = (const float*)d_in[0];
  const int*   tags      = (const int*)d_in[1];
  const float* mask      = (const float*)d_in[2];
  const float* trans     = (const float*)d_in[3];
  const float* startt    = (const float*)d_in[4];
  const float* endt      = (const float*)d_in[5];
  float* den_ws = (float*)d_ws;         // 512 floats
  float* num_ws = den_ws + Bn;          // 512 floats

  crf_numer<<<Bn, 256, 0, stream>>>(emissions, tags, mask, trans, startt, endt, num_ws);
  crf_fwd_mfma<<<NBLK, 256, 0, stream>>>(emissions, mask, trans, startt, endt, den_ws);
  reduce_loss<<<1, 512, 0, stream>>>(den_ws, num_ws, (float*)d_out);
}